// Round 5
// baseline (251.865 us; speedup 1.0000x reference)
//
#include <hip/hip_runtime.h>
#include <hip/hip_bf16.h>
#include <math.h>

#define D_MODEL 512
#define SEQ     2048
#define BATCH   4
#define NHEADS  8
#define HDIM    64
#define FFN     2048
#define TOKENS  (BATCH*SEQ)

typedef __attribute__((ext_vector_type(8))) short bf16x8;
typedef __attribute__((ext_vector_type(4))) float f32x4;
typedef __attribute__((ext_vector_type(4))) unsigned u32x4;

__device__ inline ushort f2bf(float f) {
    unsigned u = __builtin_bit_cast(unsigned, f);
    unsigned r = (u + 0x7fffu + ((u >> 16) & 1u)) >> 16;   // RNE
    return (ushort)r;
}

#define GLOAD_LDS16(g, l) __builtin_amdgcn_global_load_lds( \
    (const __attribute__((address_space(1))) void*)(g), \
    (__attribute__((address_space(3))) void*)(l), 16, 0, 0)

// ---------------- fused fp32 -> bf16 cast of x,Wqkv,Wo,W1,W2 (outputs contiguous)
__global__ void cast_all_bf16(const float* __restrict__ x, const float* __restrict__ Wqkv,
                              const float* __restrict__ Wo, const float* __restrict__ W1,
                              const float* __restrict__ W2, ushort* __restrict__ outbase) {
    const int i = blockIdx.x * blockDim.x + threadIdx.x;   // float4 index
    if (i >= 1835008) return;
    float4 v;
    if      (i < 1048576) v = ((const float4*)x)[i];
    else if (i < 1245184) v = ((const float4*)Wqkv)[i - 1048576];
    else if (i < 1310720) v = ((const float4*)Wo)[i - 1245184];
    else if (i < 1572864) v = ((const float4*)W1)[i - 1310720];
    else                  v = ((const float4*)W2)[i - 1572864];
    ushort4 o;
    o.x = f2bf(v.x); o.y = f2bf(v.y); o.z = f2bf(v.z); o.w = f2bf(v.w);
    ((ushort4*)outbase)[i] = o;
}

// ---------------- bf16 MFMA GEMM: C[M,N] = A[M,Kstride] @ W[N,Kstride]^T + bias
// MODE 1: bf16 out (+optional ReLU). MODE 2: qkv-split out. MODE 3: split-K fp32
// partials via blockIdx.z (z=0 -> CoutA with bias, z=1 -> CoutB no bias).
//
// Depth-3 K-pipeline with COUNTED vmcnt (T4): 3 LDS buffer pairs; per tile
// exactly one {s_waitcnt vmcnt(4); s_barrier}. Before computing tile t only
// stage(t+1) is outstanding (4 loads) -> vmcnt(4) proves tile t landed; the
// stage issued for t+2 right after the barrier stays in flight across TWO
// barriers. WAR safety: stage(t+2) overwrites the buffer computed at t-1;
// every wave passed barrier t only after finishing compute(t-1).
// T5: s_setprio(1) around the MFMA cluster (depth-3 gives waves role
// diversity -> scheduler can prefer the MFMA-entering wave).
//
// XCD-grouped swizzle (T1): flat id f -> XCD f%8 owns 8 consecutive
// m-panels x all n-blocks, n fastest: blocks sharing an A-panel co-resident
// on ONE XCD -> panel fetched from HBM once, L2-hit after.
//
// Bank-conflict swizzle (rule #21, verified conflicts->0): LDS slot
// (row, q16) holds global quarter q16 ^ ((row>>1)&3); LDS dest of
// global_load_lds stays LINEAR, global SOURCE column pre-swizzled, fragment
// reads XOR the same term.
template<int MODE, int RELU>
__global__ __launch_bounds__(256) void gemm_bt_mfma(const ushort* __restrict__ A,
                                                    const ushort* __restrict__ W,
                                                    const float* __restrict__ bias,
                                                    void* __restrict__ CoutA,
                                                    void* __restrict__ CoutB,
                                                    ushort* __restrict__ Qc,
                                                    ushort* __restrict__ Kc,
                                                    ushort* __restrict__ Vt,
                                                    int M, int N, int Kstride, int Klen) {
    __shared__ ushort Asb[3][128 * 32];
    __shared__ ushort Bsb[3][128 * 32];

    const int tid  = threadIdx.x;
    const int lane = tid & 63;
    const int wv   = tid >> 6;

    const int Gx = gridDim.x;
    const int f  = blockIdx.x + Gx * blockIdx.y;
    const int xc = f & 7;                 // XCD under %8 round-robin
    const int j  = f >> 3;                // [0, Gx*8)
    const int ni = j % Gx;                // n fastest within the XCD
    const int mi = xc * 8 + j / Gx;       // 8 consecutive m-panels per XCD
    const int m0 = mi * 128;
    const int n0 = ni * 128;

    const int wm   = (wv >> 1) * 64;
    const int wn   = (wv & 1) * 64;
    const int ksel = (MODE == 3) ? blockIdx.z : 0;

    const ushort* Ab = A + (size_t)ksel * Klen;
    const ushort* Wb = W + (size_t)ksel * Klen;

    // staging: thread covers LDS slot row rA (and rA+16), 16B-quarter (lane&3).
    // source column quarter = (lane&3) ^ s(row), s(row) = (row>>1)&3 = (lane>>3)&3
    const int rA = wv * 32 + (lane >> 2);
    const int cS = (((lane & 3) ^ ((lane >> 3) & 3)) * 8);
    const ushort* gA0 = Ab + (size_t)(m0 + rA) * Kstride + cS;
    const ushort* gA1 = gA0 + (size_t)16 * Kstride;
    const ushort* gB0 = Wb + (size_t)(n0 + rA) * Kstride + cS;
    const ushort* gB1 = gB0 + (size_t)16 * Kstride;

    f32x4 acc[4][4] = {};

    const int fr  = lane & 15;
    // fragment read: global quarter (lane>>4) of row r sits in LDS quarter
    // (lane>>4) ^ s(r); s(r) = (fr>>1)&3 independent of wm/i.
    const int fks = (((lane >> 4) ^ ((fr >> 1) & 3)) * 8);
    const int lo  = wv * 1024;            // this wave's staging strip (ushorts)

#define STAGE(ab, bb) do { \
        GLOAD_LDS16(gA0, (ab) + lo); \
        GLOAD_LDS16(gA1, (ab) + lo + 512); \
        GLOAD_LDS16(gB0, (bb) + lo); \
        GLOAD_LDS16(gB1, (bb) + lo + 512); \
        gA0 += 32; gA1 += 32; gB0 += 32; gB1 += 32; } while (0)

#define COMPUTE(ab, bb) do { \
        bf16x8 af_[4], bf_[4]; \
        _Pragma("unroll") \
        for (int i_ = 0; i_ < 4; ++i_) \
            af_[i_] = *(const bf16x8*)((ab) + (wm + i_ * 16 + fr) * 32 + fks); \
        _Pragma("unroll") \
        for (int j_ = 0; j_ < 4; ++j_) \
            bf_[j_] = *(const bf16x8*)((bb) + (wn + j_ * 16 + fr) * 32 + fks); \
        __builtin_amdgcn_s_setprio(1); \
        _Pragma("unroll") \
        for (int i_ = 0; i_ < 4; ++i_) \
            _Pragma("unroll") \
            for (int j_ = 0; j_ < 4; ++j_) \
                acc[i_][j_] = __builtin_amdgcn_mfma_f32_16x16x32_bf16(af_[i_], bf_[j_], acc[i_][j_], 0, 0, 0); \
        __builtin_amdgcn_s_setprio(0); \
        } while (0)

    ushort *Ac = Asb[0], *An = Asb[1], *As = Asb[2];
    ushort *Bc = Bsb[0], *Bn = Bsb[1], *Bs = Bsb[2];

    STAGE(Ac, Bc);                        // tile 0
    STAGE(An, Bn);                        // tile 1
    const int ntiles = Klen >> 5;         // >= 8 for all our shapes
    for (int t = 0; t < ntiles - 1; ++t) {
        asm volatile("s_waitcnt vmcnt(4)" ::: "memory");
        __builtin_amdgcn_s_barrier();
        __builtin_amdgcn_sched_barrier(0);
        if (t + 2 < ntiles) STAGE(As, Bs);
        COMPUTE(Ac, Bc);
        ushort* tA = Ac; Ac = An; An = As; As = tA;
        ushort* tB = Bc; Bc = Bn; Bn = Bs; Bs = tB;
    }
    asm volatile("s_waitcnt vmcnt(0)" ::: "memory");
    __builtin_amdgcn_s_barrier();
    __builtin_amdgcn_sched_barrier(0);
    COMPUTE(Ac, Bc);

#undef STAGE
#undef COMPUTE

    const int col  = lane & 15;
    const int rowq = (lane >> 4) * 4;
    #pragma unroll
    for (int i = 0; i < 4; ++i) {
        const int gm = m0 + wm + i * 16 + rowq;
        #pragma unroll
        for (int j2 = 0; j2 < 4; ++j2) {
            const int gn = n0 + wn + j2 * 16 + col;
            if (MODE == 2) {
                const float bv = bias[gn];
                const int seg = gn >> 9;
                const int h   = (gn >> 6) & 7;
                const int dd  = gn & 63;
                const int bb  = gm >> 11;
                const int ss  = gm & 2047;
                const int bh  = bb * 8 + h;
                if (seg == 2) {
                    ushort4 pk;
                    pk.x = f2bf(acc[i][j2][0] + bv);
                    pk.y = f2bf(acc[i][j2][1] + bv);
                    pk.z = f2bf(acc[i][j2][2] + bv);
                    pk.w = f2bf(acc[i][j2][3] + bv);
                    *(ushort4*)(Vt + ((size_t)bh * 64 + dd) * 2048 + ss) = pk;
                } else {
                    ushort* dst = (seg == 0 ? Qc : Kc) + ((size_t)bh * 2048 + ss) * 64 + dd;
                    #pragma unroll
                    for (int r = 0; r < 4; ++r)
                        dst[(size_t)r * 64] = f2bf(acc[i][j2][r] + bv);
                }
            } else if (MODE == 3) {
                float* dst = (float*)(ksel ? CoutB : CoutA);
                const float bv = ksel ? 0.f : bias[gn];
                #pragma unroll
                for (int r = 0; r < 4; ++r)
                    dst[(size_t)(gm + r) * N + gn] = acc[i][j2][r] + bv;
            } else {
                const float bv = bias[gn];
                #pragma unroll
                for (int r = 0; r < 4; ++r) {
                    float v = acc[i][j2][r] + bv;
                    if (RELU) v = fmaxf(v, 0.f);
                    ((ushort*)CoutA)[(size_t)(gm + r) * N + gn] = f2bf(v);
                }
            }
        }
    }
}

// ---------------- one q-tile step, max-free online softmax, in-register P.
// QK^T computed SWAPPED: s = mfma(K, Q) -> lane (col,g) reg r holds
// S[k = j0 + nt*16 + 4g + r][q = qw + col]  (A/B fragments share one layout,
// so kf/qf are the same bytes as the unswapped version).
// P->A-fragment transpose is pure-register: pack r-pairs to bf16x2 words
// W[2*nt+slot] (flat reg bits = (nt1, nt0, slot)), then exchange
// lane-bit5<->regbit1 (permlane32_swap) and lane-bit4<->regbit1
// (permlane16_swap). Final coords: lane (col,g) holds P[q=qw+col][k=8g..8g+7]
// (pf0, regs W0-W3) and k=32+8g.. (pf1, W4-W7): exactly the PV A-fragment.
__device__ __forceinline__ void attn_step(const ushort* __restrict__ Kb,
                                          const ushort* __restrict__ Vb,
                                          bf16x8 qf0, bf16x8 qf1,
                                          float& lp, f32x4 (&o)[4],
                                          int qw, int j0, bool diag,
                                          int col, int g, int c7) {
    f32x4 s[4] = {};
    __builtin_amdgcn_s_setprio(1);
    #pragma unroll
    for (int nt = 0; nt < 4; ++nt) {
        const int kr = nt * 16 + col;
        bf16x8 kf0 = *(const bf16x8*)(Kb + kr * 64 + (((g    ) ^ c7) * 8));
        bf16x8 kf1 = *(const bf16x8*)(Kb + kr * 64 + (((g + 4) ^ c7) * 8));
        s[nt] = __builtin_amdgcn_mfma_f32_16x16x32_bf16(kf0, qf0, s[nt], 0, 0, 0);
        s[nt] = __builtin_amdgcn_mfma_f32_16x16x32_bf16(kf1, qf1, s[nt], 0, 0, 0);
    }
    __builtin_amdgcn_s_setprio(0);

    if (diag) {
        #pragma unroll
        for (int nt = 0; nt < 4; ++nt)
            #pragma unroll
            for (int r = 0; r < 4; ++r)
                if ((j0 + nt * 16 + 4 * g + r) > (qw + col)) s[nt][r] = -INFINITY;
    }

    // p = exp(s/8); per-lane l partial is for the single q = qw+col
    unsigned W[8];
    #pragma unroll
    for (int nt = 0; nt < 4; ++nt) {
        float p0 = __expf(s[nt][0] * 0.125f);
        float p1 = __expf(s[nt][1] * 0.125f);
        float p2 = __expf(s[nt][2] * 0.125f);
        float p3 = __expf(s[nt][3] * 0.125f);
        lp += (p0 + p1) + (p2 + p3);
        asm("v_cvt_pk_bf16_f32 %0, %1, %2" : "=v"(W[2 * nt])     : "v"(p0), "v"(p1));
        asm("v_cvt_pk_bf16_f32 %0, %1, %2" : "=v"(W[2 * nt + 1]) : "v"(p2), "v"(p3));
    }
    // lane-bit5 <-> reg-bit1:  X'={X.lo,Y.lo}, Y'={X.hi,Y.hi}
    asm("v_permlane32_swap_b32 %0, %1" : "+v"(W[0]), "+v"(W[2]));
    asm("v_permlane32_swap_b32 %0, %1" : "+v"(W[1]), "+v"(W[3]));
    asm("v_permlane32_swap_b32 %0, %1" : "+v"(W[4]), "+v"(W[6]));
    asm("v_permlane32_swap_b32 %0, %1" : "+v"(W[5]), "+v"(W[7]));
    // lane-bit4 <-> reg-bit1 (within each 32-half): X'={X.r0,Y.r0}, Y'={X.r1,Y.r1}
    asm("v_permlane16_swap_b32 %0, %1" : "+v"(W[0]), "+v"(W[2]));
    asm("v_permlane16_swap_b32 %0, %1" : "+v"(W[1]), "+v"(W[3]));
    asm("v_permlane16_swap_b32 %0, %1" : "+v"(W[4]), "+v"(W[6]));
    asm("v_permlane16_swap_b32 %0, %1" : "+v"(W[5]), "+v"(W[7]));

    u32x4 wa = {W[0], W[1], W[2], W[3]};
    u32x4 wb = {W[4], W[5], W[6], W[7]};
    bf16x8 pf0 = __builtin_bit_cast(bf16x8, wa);
    bf16x8 pf1 = __builtin_bit_cast(bf16x8, wb);

    __builtin_amdgcn_s_setprio(1);
    #pragma unroll
    for (int nt = 0; nt < 4; ++nt) {
        const int vr = nt * 16 + col;
        bf16x8 vf0 = *(const bf16x8*)(Vb + vr * 64 + (((g    ) ^ c7) * 8));
        bf16x8 vf1 = *(const bf16x8*)(Vb + vr * 64 + (((g + 4) ^ c7) * 8));
        o[nt] = __builtin_amdgcn_mfma_f32_16x16x32_bf16(pf0, vf0, o[nt], 0, 0, 0);
        o[nt] = __builtin_amdgcn_mfma_f32_16x16x32_bf16(pf1, vf1, o[nt], 0, 0, 0);
    }
    __builtin_amdgcn_s_setprio(0);
}

// ---------------- MFMA flash attention, ONE q-tile per block (fine-grained).
// Grid 1024 blocks -> 4 blocks/CU resident (LDS 32KB, launch_bounds(256,4));
// previous paired-q-tile version was 512 blocks = 2/CU and latency-bound
// (MfmaUtil 14% with MFMA+VALU floors ~5us vs ~38us measured). Cross-wave
// TLP (16 waves/CU) now covers the per-step dependency chain.
// Mapping: XCD c = idx&7 owns bh {4c..4c+3} (K/V working set 2MB < 4MB L2);
// within an XCD, q-tiles issue LONGEST-FIRST (slot>>2 ascending -> qt
// descending) so 32-step blocks start early and 1-step blocks fill the tail.
__global__ __launch_bounds__(256, 4) void attn_mfma_kernel(const ushort* __restrict__ Qc,
                                                           const ushort* __restrict__ Kc,
                                                           const ushort* __restrict__ Vt,
                                                           ushort* __restrict__ ctxb) {
    __shared__ ushort Ks[2 * 64 * 64];
    __shared__ ushort Vs[2 * 64 * 64];

    const int tid  = threadIdx.x;
    const int lane = tid & 63;
    const int wv   = tid >> 6;
    const int idx  = blockIdx.x;                // 0..1023
    const int slot = idx >> 3;                  // 0..127
    const int bh   = (idx & 7) * 4 + (slot & 3);
    const int qt   = 31 - (slot >> 2);          // longest-first
    const int q0   = qt * 64;
    const int qw   = q0 + wv * 16;

    const int col = lane & 15;
    const int g   = lane >> 4;
    const int c7  = col & 7;

    bf16x8 qf0, qf1;
    {
        const ushort* qa = Qc + ((size_t)bh * 2048 + qw + col) * 64 + g * 8;
        qf0 = *(const bf16x8*)qa;
        qf1 = *(const bf16x8*)(qa + 32);
    }

    const int srow = tid >> 2;
    const int sch  = 2 * (tid & 3);
    const ushort* Kg = Kc + ((size_t)bh * 2048 + srow) * 64 + sch * 8;
    const ushort* Vg = Vt + ((size_t)bh * 64 + srow) * 2048 + sch * 8;
    const int ko0 = srow * 64 + (((sch    ) ^ (srow & 7)) * 8);
    const int ko1 = srow * 64 + (((sch + 1) ^ (srow & 7)) * 8);

    float lp = 0.f;
    f32x4 o[4] = {};

    bf16x8 pk0 = *(const bf16x8*)(Kg);
    bf16x8 pk1 = *(const bf16x8*)(Kg + 8);
    bf16x8 pv0 = *(const bf16x8*)(Vg);
    bf16x8 pv1 = *(const bf16x8*)(Vg + 8);

    for (int j0 = 0; j0 <= q0; j0 += 64) {
        const int par = (j0 >> 6) & 1;
        ushort* Kb = Ks + par * 4096;
        ushort* Vb = Vs + par * 4096;
        *(bf16x8*)(Kb + ko0) = pk0; *(bf16x8*)(Kb + ko1) = pk1;
        *(bf16x8*)(Vb + ko0) = pv0; *(bf16x8*)(Vb + ko1) = pv1;
        __syncthreads();

        if (j0 < q0) {
            pk0 = *(const bf16x8*)(Kg + (size_t)(j0 + 64) * 64);
            pk1 = *(const bf16x8*)(Kg + (size_t)(j0 + 64) * 64 + 8);
            pv0 = *(const bf16x8*)(Vg + j0 + 64);
            pv1 = *(const bf16x8*)(Vg + j0 + 72);
        }

        attn_step(Kb, Vb, qf0, qf1, lp, o, qw, j0, j0 == q0, col, g, c7);
    }

    // epilogue: l[q=qw+col] replicated in the 4 g-lanes of each col group;
    // reduce across g (xor 16/32), then gather l for q=4g+r via lane shuffle.
    float la = lp; la += __shfl_xor(la, 16); la += __shfl_xor(la, 32);
    const int b = bh >> 3, h = bh & 7;
    #pragma unroll
    for (int r = 0; r < 4; ++r) {
        const float inva = 1.f / __shfl(la, 4 * g + r);
        const size_t rowa = ((size_t)b * 2048 + qw + 4 * g + r) * 512 + h * 64;
        #pragma unroll
        for (int nt = 0; nt < 4; ++nt)
            ctxb[rowa + nt * 16 + col] = f2bf(o[nt][r] * inva);
    }
}

// ---------------- LayerNorm(residual): out = LN(A + B1 [+ B2]) * g + beta
template<int WRITE_BF16>
__global__ void ln_residual(const float* __restrict__ A, const float* __restrict__ B1,
                            const float* __restrict__ B2,
                            const float* __restrict__ g, const float* __restrict__ beta,
                            float* __restrict__ out, ushort* __restrict__ outb) {
    __shared__ float sbuf[8];
    const int row = blockIdx.x;
    const int tid = threadIdx.x;
    const size_t base = (size_t)row * D_MODEL;

    float v0 = A[base + tid]       + B1[base + tid]       + B2[base + tid];
    float v1 = A[base + tid + 256] + B1[base + tid + 256] + B2[base + tid + 256];

    float sum = v0 + v1;
    #pragma unroll
    for (int off = 32; off; off >>= 1) sum += __shfl_xor(sum, off);
    if ((tid & 63) == 0) sbuf[tid >> 6] = sum;
    __syncthreads();
    if (tid == 0) { float t = 0.f; for (int i = 0; i < 4; ++i) t += sbuf[i]; sbuf[4] = t; }
    __syncthreads();
    const float mu = sbuf[4] * (1.f / 512.f);
    __syncthreads();

    float d0 = v0 - mu, d1 = v1 - mu;
    float sq = d0 * d0 + d1 * d1;
    #pragma unroll
    for (int off = 32; off; off >>= 1) sq += __shfl_xor(sq, off);
    if ((tid & 63) == 0) sbuf[tid >> 6] = sq;
    __syncthreads();
    if (tid == 0) { float t = 0.f; for (int i = 0; i < 4; ++i) t += sbuf[i]; sbuf[4] = t; }
    __syncthreads();
    const float var = sbuf[4] * (1.f / 512.f);
    const float rs  = rsqrtf(var + 1e-5f);

    float r0 = d0 * rs * g[tid]       + beta[tid];
    float r1 = d1 * rs * g[tid + 256] + beta[tid + 256];
    out[base + tid]       = r0;
    out[base + tid + 256] = r1;
    if (WRITE_BF16) {
        outb[base + tid]       = f2bf(r0);
        outb[base + tid + 256] = f2bf(r1);
    }
}

extern "C" void kernel_launch(void* const* d_in, const int* in_sizes, int n_in,
                              void* d_out, int out_size, void* d_ws, size_t ws_size,
                              hipStream_t stream) {
    const float* x    = (const float*)d_in[0];
    const float* Wqkv = (const float*)d_in[1];
    const float* bqkv = (const float*)d_in[2];
    const float* Wo   = (const float*)d_in[3];
    const float* bo   = (const float*)d_in[4];
    const float* W1   = (const float*)d_in[5];
    const float* b1   = (const float*)d_in[6];
    const float* W2   = (const float*)d_in[7];
    const float* b2   = (const float*)d_in[8];
    const float* g1   = (const float*)d_in[9];
    const float* bn1  = (const float*)d_in[10];
    const float* g2   = (const float*)d_in[11];
    const float* bn2  = (const float*)d_in[12];

    float* ws = (float*)d_ws;
    // time-multiplexed layout (floats):
    // [0,6291456)    Qcb/Kcb/Vtb (steps 1-2); attn_b partial [0,4194304) (step 3-4);
    //                ff1b [0,8388608) (steps 5-6)
    // [8388608,12582912)  ff2a (steps 6-7)
    // [12582912,16777216) attn_a (steps 3-4); ff2b (steps 6-7)
    // [16777216,20971520) ln1 fp32
    // [20971520,...) ctxb, ln1b, xb, Wqkvb, Wob, W1b, W2b (bf16)
    ushort* Qcb     = (ushort*)ws;
    ushort* Kcb     = (ushort*)(ws + 2097152);
    ushort* Vtb     = (ushort*)(ws + 4194304);
    float*  attn_b  = ws;
    ushort* ff1b    = (ushort*)ws;
    float*  ff2a    = ws + 8388608;
    float*  attn_a  = ws + 12582912;
    float*  ff2b    = ws + 12582912;
    float*  ln1     = ws + 16777216;
    ushort* ctxb  = (ushort*)(ws + 20971520);
    ushort* ln1b  = (ushort*)(ws + 23068672);
    ushort* xb    = (ushort*)(ws + 25165824);
    ushort* Wqkvb = (ushort*)(ws + 27262976);
    float*  out   = (float*)d_out;
    ushort* W1b   = (ushort*)(ws + 27787264);
    ushort* W2b   = (ushort*)(ws + 28311552);
    ushort* Wob   = (ushort*)(ws + 27656192);

    const dim3 blk(256);

    // 0. fused casts (xb..W2b contiguous from xb)
    cast_all_bf16<<<dim3(7168), blk, 0, stream>>>(x, Wqkv, Wo, W1, W2, xb);

    // 1. QKV projection -> split Qc/Kc/Vt bf16
    gemm_bt_mfma<2,0><<<dim3(1536/128, 8192/128), blk, 0, stream>>>(
        xb, Wqkvb, bqkv, nullptr, nullptr, Qcb, Kcb, Vtb, TOKENS, 1536, 512, 512);
    // 2. MFMA flash attention (1 q-tile/block, longest-first, XCD-grouped) -> ctxb
    attn_mfma_kernel<<<dim3(1024), blk, 0, stream>>>(Qcb, Kcb, Vtb, ctxb);
    // 3. output projection, split-K=2 -> attn_a (bias) + attn_b
    gemm_bt_mfma<3,0><<<dim3(512/128, 8192/128, 2), blk, 0, stream>>>(
        ctxb, Wob, bo, attn_a, attn_b, nullptr, nullptr, nullptr, TOKENS, 512, 512, 256);
    // 4. LN1(x + attn_a + attn_b) -> ln1 fp32 + ln1b bf16
    ln_residual<1><<<dim3(TOKENS), blk, 0, stream>>>(x, attn_a, attn_b, g1, bn1, ln1, ln1b);
    // 5. FF1 + ReLU -> ff1b bf16 [8192,2048]
    gemm_bt_mfma<1,1><<<dim3(2048/128, 8192/128), blk, 0, stream>>>(
        ln1b, W1b, b1, ff1b, nullptr, nullptr, nullptr, nullptr, TOKENS, 2048, 512, 512);
    // 6. FF2, split-K=2 -> ff2a (bias) + ff2b
    gemm_bt_mfma<3,0><<<dim3(512/128, 8192/128, 2), blk, 0, stream>>>(
        ff1b, W2b, b2, ff2a, ff2b, nullptr, nullptr, nullptr, TOKENS, 512, 2048, 1024);
    // 7. LN2(ln1 + ff2a + ff2b) -> out
    ln_residual<0><<<dim3(TOKENS), blk, 0, stream>>>(ln1, ff2a, ff2b, g2, bn2, out, nullptr);
}

// Round 6
// 246.703 us; speedup vs baseline: 1.0209x; 1.0209x over previous
//
#include <hip/hip_runtime.h>
#include <hip/hip_bf16.h>
#include <math.h>

#define D_MODEL 512
#define SEQ     2048
#define BATCH   4
#define NHEADS  8
#define HDIM    64
#define FFN     2048
#define TOKENS  (BATCH*SEQ)

typedef __attribute__((ext_vector_type(8))) short bf16x8;
typedef __attribute__((ext_vector_type(4))) float f32x4;
typedef __attribute__((ext_vector_type(4))) unsigned u32x4;

__device__ inline ushort f2bf(float f) {
    unsigned u = __builtin_bit_cast(unsigned, f);
    unsigned r = (u + 0x7fffu + ((u >> 16) & 1u)) >> 16;   // RNE
    return (ushort)r;
}

#define GLOAD_LDS16(g, l) __builtin_amdgcn_global_load_lds( \
    (const __attribute__((address_space(1))) void*)(g), \
    (__attribute__((address_space(3))) void*)(l), 16, 0, 0)

// ---------------- fused fp32 -> bf16 cast of x,Wqkv,Wo,W1,W2 (outputs contiguous)
__global__ void cast_all_bf16(const float* __restrict__ x, const float* __restrict__ Wqkv,
                              const float* __restrict__ Wo, const float* __restrict__ W1,
                              const float* __restrict__ W2, ushort* __restrict__ outbase) {
    const int i = blockIdx.x * blockDim.x + threadIdx.x;   // float4 index
    if (i >= 1835008) return;
    float4 v;
    if      (i < 1048576) v = ((const float4*)x)[i];
    else if (i < 1245184) v = ((const float4*)Wqkv)[i - 1048576];
    else if (i < 1310720) v = ((const float4*)Wo)[i - 1245184];
    else if (i < 1572864) v = ((const float4*)W1)[i - 1310720];
    else                  v = ((const float4*)W2)[i - 1572864];
    ushort4 o;
    o.x = f2bf(v.x); o.y = f2bf(v.y); o.z = f2bf(v.z); o.w = f2bf(v.w);
    ((ushort4*)outbase)[i] = o;
}

// ---------------- bf16 MFMA GEMM: C[M,N] = A[M,Kstride] @ W[N,Kstride]^T + bias
// MODE 1: bf16 out (+optional ReLU). MODE 2: qkv-split out. MODE 3: fp32 out
// with bias (full-K; replaces the old split-K path -- the fp32 partial
// write+read traffic (64MB) cost ~15us of HBM; BM=64 gives the same 512-block
// grid without it).
// BM: 128 (tile 128x128, 4 waves 2x2, wave 64x64) or 64 (tile 64x128, wave
// 32x64, LDS 36KB -> 4 blocks/CU, used for the N=512 GEMMs Wo/FF2).
//
// Depth-3 K-pipeline with COUNTED vmcnt (T4): 3 LDS buffer pairs; per tile
// exactly one {s_waitcnt vmcnt(L); s_barrier} where L = loads of stage(t+1)
// still outstanding (4 for BM=128, 3 for BM=64). The stage issued for t+2
// right after the barrier stays in flight across TWO barriers. WAR safety:
// stage(t+2) overwrites the buffer computed at t-1; every wave passed
// barrier t only after finishing compute(t-1).
//
// XCD-grouped swizzle (T1): flat id f -> XCD f%8 owns gridDim.y/8
// consecutive m-panels x all n-blocks, n fastest: blocks sharing an A-panel
// co-resident on ONE XCD -> panel fetched from HBM once, L2-hit after.
//
// Bank-conflict swizzle (rule #21, verified conflicts->0): LDS slot
// (row, q16) holds global quarter q16 ^ ((row>>1)&3); LDS dest of
// global_load_lds stays LINEAR, global SOURCE column pre-swizzled, fragment
// reads XOR the same term.
template<int MODE, int RELU, int BM>
__global__ __launch_bounds__(256) void gemm_bt_mfma(const ushort* __restrict__ A,
                                                    const ushort* __restrict__ W,
                                                    const float* __restrict__ bias,
                                                    void* __restrict__ CoutA,
                                                    ushort* __restrict__ Qc,
                                                    ushort* __restrict__ Kc,
                                                    ushort* __restrict__ Vt,
                                                    int M, int N, int Kstride, int Klen) {
    constexpr int MI = BM / 32;           // m-fragments per wave
    __shared__ ushort Asb[3][BM * 32];
    __shared__ ushort Bsb[3][128 * 32];

    const int tid  = threadIdx.x;
    const int lane = tid & 63;
    const int wv   = tid >> 6;

    const int Gx = gridDim.x;
    const int f  = blockIdx.x + Gx * blockIdx.y;
    const int xc = f & 7;                 // XCD under %8 round-robin
    const int j  = f >> 3;
    const int ni = j % Gx;                // n fastest within the XCD
    const int mi = xc * (gridDim.y >> 3) + j / Gx;
    const int m0 = mi * BM;
    const int n0 = ni * 128;

    const int wm = (wv >> 1) * (BM / 2);
    const int wn = (wv & 1) * 64;

    // staging: thread covers LDS slot row rA/rB, 16B-quarter (lane&3).
    // source column quarter = (lane&3) ^ s(row), s(row)=(row>>1)&3=(lane>>3)&3
    const int rA = wv * (BM / 4) + (lane >> 2);
    const int rB = wv * 32 + (lane >> 2);
    const int cS = (((lane & 3) ^ ((lane >> 3) & 3)) * 8);
    const ushort* gA0 = A + (size_t)(m0 + rA) * Kstride + cS;
    const ushort* gA1 = gA0 + (size_t)16 * Kstride;     // used only if BM==128
    const ushort* gB0 = W + (size_t)(n0 + rB) * Kstride + cS;
    const ushort* gB1 = gB0 + (size_t)16 * Kstride;

    f32x4 acc[MI][4] = {};

    const int fr  = lane & 15;
    // fragment read: global quarter (lane>>4) of row r sits in LDS quarter
    // (lane>>4) ^ s(r); s(r) = (fr>>1)&3 independent of wm/i.
    const int fks = (((lane >> 4) ^ ((fr >> 1) & 3)) * 8);
    const int loA = wv * (BM * 32 / 4);   // this wave's A staging strip
    const int loB = wv * 1024;

#define STAGE(ab, bb) do { \
        GLOAD_LDS16(gA0, (ab) + loA); \
        if constexpr (BM == 128) GLOAD_LDS16(gA1, (ab) + loA + 512); \
        GLOAD_LDS16(gB0, (bb) + loB); \
        GLOAD_LDS16(gB1, (bb) + loB + 512); \
        gA0 += 32; if constexpr (BM == 128) gA1 += 32; \
        gB0 += 32; gB1 += 32; } while (0)

#define COMPUTE(ab, bb) do { \
        bf16x8 af_[MI], bf_[4]; \
        _Pragma("unroll") \
        for (int i_ = 0; i_ < MI; ++i_) \
            af_[i_] = *(const bf16x8*)((ab) + (wm + i_ * 16 + fr) * 32 + fks); \
        _Pragma("unroll") \
        for (int j_ = 0; j_ < 4; ++j_) \
            bf_[j_] = *(const bf16x8*)((bb) + (wn + j_ * 16 + fr) * 32 + fks); \
        _Pragma("unroll") \
        for (int i_ = 0; i_ < MI; ++i_) \
            _Pragma("unroll") \
            for (int j_ = 0; j_ < 4; ++j_) \
                acc[i_][j_] = __builtin_amdgcn_mfma_f32_16x16x32_bf16(af_[i_], bf_[j_], acc[i_][j_], 0, 0, 0); \
        } while (0)

#define PWAIT do { \
        if constexpr (BM == 128) asm volatile("s_waitcnt vmcnt(4)" ::: "memory"); \
        else                     asm volatile("s_waitcnt vmcnt(3)" ::: "memory"); \
        __builtin_amdgcn_s_barrier(); \
        __builtin_amdgcn_sched_barrier(0); } while (0)

    ushort *Ac = Asb[0], *An = Asb[1], *As = Asb[2];
    ushort *Bc = Bsb[0], *Bn = Bsb[1], *Bs = Bsb[2];

    STAGE(Ac, Bc);                        // tile 0
    STAGE(An, Bn);                        // tile 1
    const int ntiles = Klen >> 5;         // >= 8 for all our shapes
    for (int t = 0; t < ntiles - 1; ++t) {
        PWAIT;
        if (t + 2 < ntiles) STAGE(As, Bs);
        COMPUTE(Ac, Bc);
        ushort* tA = Ac; Ac = An; An = As; As = tA;
        ushort* tB = Bc; Bc = Bn; Bn = Bs; Bs = tB;
    }
    asm volatile("s_waitcnt vmcnt(0)" ::: "memory");
    __builtin_amdgcn_s_barrier();
    __builtin_amdgcn_sched_barrier(0);
    COMPUTE(Ac, Bc);

#undef STAGE
#undef COMPUTE
#undef PWAIT

    const int col  = lane & 15;
    const int rowq = (lane >> 4) * 4;
    #pragma unroll
    for (int i = 0; i < MI; ++i) {
        const int gm = m0 + wm + i * 16 + rowq;
        #pragma unroll
        for (int j2 = 0; j2 < 4; ++j2) {
            const int gn = n0 + wn + j2 * 16 + col;
            if (MODE == 2) {
                const float bv = bias[gn];
                const int seg = gn >> 9;
                const int h   = (gn >> 6) & 7;
                const int dd  = gn & 63;
                const int bb  = gm >> 11;
                const int ss  = gm & 2047;
                const int bh  = bb * 8 + h;
                if (seg == 2) {
                    ushort4 pk;
                    pk.x = f2bf(acc[i][j2][0] + bv);
                    pk.y = f2bf(acc[i][j2][1] + bv);
                    pk.z = f2bf(acc[i][j2][2] + bv);
                    pk.w = f2bf(acc[i][j2][3] + bv);
                    *(ushort4*)(Vt + ((size_t)bh * 64 + dd) * 2048 + ss) = pk;
                } else {
                    ushort* dst = (seg == 0 ? Qc : Kc) + ((size_t)bh * 2048 + ss) * 64 + dd;
                    #pragma unroll
                    for (int r = 0; r < 4; ++r)
                        dst[(size_t)r * 64] = f2bf(acc[i][j2][r] + bv);
                }
            } else if (MODE == 3) {
                float* dst = (float*)CoutA;
                const float bv = bias[gn];
                #pragma unroll
                for (int r = 0; r < 4; ++r)
                    dst[(size_t)(gm + r) * N + gn] = acc[i][j2][r] + bv;
            } else {
                const float bv = bias[gn];
                #pragma unroll
                for (int r = 0; r < 4; ++r) {
                    float v = acc[i][j2][r] + bv;
                    if (RELU) v = fmaxf(v, 0.f);
                    ((ushort*)CoutA)[(size_t)(gm + r) * N + gn] = f2bf(v);
                }
            }
        }
    }
}

// ---------------- one q-tile step, max-free online softmax, in-register P.
// QK^T computed SWAPPED: s = mfma(K, Q) -> lane (col,g) reg r holds
// S[k = j0 + nt*16 + 4g + r][q = qw + col]  (A/B fragments share one layout,
// so kf/qf are the same bytes as the unswapped version).
// P->A-fragment transpose is pure-register: pack r-pairs to bf16x2 words
// W[2*nt+slot] (flat reg bits = (nt1, nt0, slot)), then exchange
// lane-bit5<->regbit1 (permlane32_swap) and lane-bit4<->regbit1
// (permlane16_swap). Final coords: lane (col,g) holds P[q=qw+col][k=8g..8g+7]
// (pf0, regs W0-W3) and k=32+8g.. (pf1, W4-W7): exactly the PV A-fragment.
// T5 setprio(1) around both MFMA clusters (catalog: +4-7% on attn).
__device__ __forceinline__ void attn_step(const ushort* __restrict__ Kb,
                                          const ushort* __restrict__ Vb,
                                          bf16x8 qf0, bf16x8 qf1,
                                          float& lp, f32x4 (&o)[4],
                                          int qw, int j0, bool diag,
                                          int col, int g, int c7) {
    f32x4 s[4] = {};
    __builtin_amdgcn_s_setprio(1);
    #pragma unroll
    for (int nt = 0; nt < 4; ++nt) {
        const int kr = nt * 16 + col;
        bf16x8 kf0 = *(const bf16x8*)(Kb + kr * 64 + (((g    ) ^ c7) * 8));
        bf16x8 kf1 = *(const bf16x8*)(Kb + kr * 64 + (((g + 4) ^ c7) * 8));
        s[nt] = __builtin_amdgcn_mfma_f32_16x16x32_bf16(kf0, qf0, s[nt], 0, 0, 0);
        s[nt] = __builtin_amdgcn_mfma_f32_16x16x32_bf16(kf1, qf1, s[nt], 0, 0, 0);
    }
    __builtin_amdgcn_s_setprio(0);

    if (diag) {
        #pragma unroll
        for (int nt = 0; nt < 4; ++nt)
            #pragma unroll
            for (int r = 0; r < 4; ++r)
                if ((j0 + nt * 16 + 4 * g + r) > (qw + col)) s[nt][r] = -INFINITY;
    }

    // p = exp(s/8); per-lane l partial is for the single q = qw+col
    unsigned W[8];
    #pragma unroll
    for (int nt = 0; nt < 4; ++nt) {
        float p0 = __expf(s[nt][0] * 0.125f);
        float p1 = __expf(s[nt][1] * 0.125f);
        float p2 = __expf(s[nt][2] * 0.125f);
        float p3 = __expf(s[nt][3] * 0.125f);
        lp += (p0 + p1) + (p2 + p3);
        asm("v_cvt_pk_bf16_f32 %0, %1, %2" : "=v"(W[2 * nt])     : "v"(p0), "v"(p1));
        asm("v_cvt_pk_bf16_f32 %0, %1, %2" : "=v"(W[2 * nt + 1]) : "v"(p2), "v"(p3));
    }
    // lane-bit5 <-> reg-bit1:  X'={X.lo,Y.lo}, Y'={X.hi,Y.hi}
    asm("v_permlane32_swap_b32 %0, %1" : "+v"(W[0]), "+v"(W[2]));
    asm("v_permlane32_swap_b32 %0, %1" : "+v"(W[1]), "+v"(W[3]));
    asm("v_permlane32_swap_b32 %0, %1" : "+v"(W[4]), "+v"(W[6]));
    asm("v_permlane32_swap_b32 %0, %1" : "+v"(W[5]), "+v"(W[7]));
    // lane-bit4 <-> reg-bit1 (within each 32-half): X'={X.r0,Y.r0}, Y'={X.r1,Y.r1}
    asm("v_permlane16_swap_b32 %0, %1" : "+v"(W[0]), "+v"(W[2]));
    asm("v_permlane16_swap_b32 %0, %1" : "+v"(W[1]), "+v"(W[3]));
    asm("v_permlane16_swap_b32 %0, %1" : "+v"(W[4]), "+v"(W[6]));
    asm("v_permlane16_swap_b32 %0, %1" : "+v"(W[5]), "+v"(W[7]));

    u32x4 wa = {W[0], W[1], W[2], W[3]};
    u32x4 wb = {W[4], W[5], W[6], W[7]};
    bf16x8 pf0 = __builtin_bit_cast(bf16x8, wa);
    bf16x8 pf1 = __builtin_bit_cast(bf16x8, wb);

    __builtin_amdgcn_s_setprio(1);
    #pragma unroll
    for (int nt = 0; nt < 4; ++nt) {
        const int vr = nt * 16 + col;
        bf16x8 vf0 = *(const bf16x8*)(Vb + vr * 64 + (((g    ) ^ c7) * 8));
        bf16x8 vf1 = *(const bf16x8*)(Vb + vr * 64 + (((g + 4) ^ c7) * 8));
        o[nt] = __builtin_amdgcn_mfma_f32_16x16x32_bf16(pf0, vf0, o[nt], 0, 0, 0);
        o[nt] = __builtin_amdgcn_mfma_f32_16x16x32_bf16(pf1, vf1, o[nt], 0, 0, 0);
    }
    __builtin_amdgcn_s_setprio(0);
}

// ---------------- MFMA flash attention, paired q-tiles, K/V LDS double-buffer.
// (round-4 structure, best measured: one K/V stage amortized over up to two
// attn_steps; un-paired 1024-block variant regressed -3us in round 5.)
// XCD swizzle: all 16 pair-blocks of a bh land on one XCD -> per-XCD K/V
// working set = 4 heads * 512KB = 2MB < 4MB L2.
__global__ __launch_bounds__(256, 4) void attn_mfma_kernel(const ushort* __restrict__ Qc,
                                                           const ushort* __restrict__ Kc,
                                                           const ushort* __restrict__ Vt,
                                                           ushort* __restrict__ ctxb) {
    __shared__ ushort Ks[2 * 64 * 64];
    __shared__ ushort Vs[2 * 64 * 64];

    const int tid  = threadIdx.x;
    const int lane = tid & 63;
    const int wv   = tid >> 6;
    const int idx  = blockIdx.x;                // 0..511
    const int bh   = (idx & 7) * 4 + (idx >> 7);
    const int pair = (idx >> 3) & 15;
    const int q0a  = pair * 64;
    const int q0b  = (31 - pair) * 64;
    const int qwA  = q0a + wv * 16;
    const int qwB  = q0b + wv * 16;

    const int col = lane & 15;
    const int g   = lane >> 4;
    const int c7  = col & 7;

    bf16x8 qfA0, qfA1, qfB0, qfB1;
    {
        const ushort* qa = Qc + ((size_t)bh * 2048 + qwA + col) * 64 + g * 8;
        qfA0 = *(const bf16x8*)qa;
        qfA1 = *(const bf16x8*)(qa + 32);
        const ushort* qb = Qc + ((size_t)bh * 2048 + qwB + col) * 64 + g * 8;
        qfB0 = *(const bf16x8*)qb;
        qfB1 = *(const bf16x8*)(qb + 32);
    }

    const int srow = tid >> 2;
    const int sch  = 2 * (tid & 3);
    const ushort* Kg = Kc + ((size_t)bh * 2048 + srow) * 64 + sch * 8;
    const ushort* Vg = Vt + ((size_t)bh * 64 + srow) * 2048 + sch * 8;
    const int ko0 = srow * 64 + (((sch    ) ^ (srow & 7)) * 8);
    const int ko1 = srow * 64 + (((sch + 1) ^ (srow & 7)) * 8);

    float lpa = 0.f, lpb = 0.f;
    f32x4 oa[4] = {}, ob[4] = {};

    bf16x8 pk0 = *(const bf16x8*)(Kg);
    bf16x8 pk1 = *(const bf16x8*)(Kg + 8);
    bf16x8 pv0 = *(const bf16x8*)(Vg);
    bf16x8 pv1 = *(const bf16x8*)(Vg + 8);

    for (int j0 = 0; j0 <= q0b; j0 += 64) {
        const int par = (j0 >> 6) & 1;
        ushort* Kb = Ks + par * 4096;
        ushort* Vb = Vs + par * 4096;
        *(bf16x8*)(Kb + ko0) = pk0; *(bf16x8*)(Kb + ko1) = pk1;
        *(bf16x8*)(Vb + ko0) = pv0; *(bf16x8*)(Vb + ko1) = pv1;
        __syncthreads();

        if (j0 < q0b) {
            pk0 = *(const bf16x8*)(Kg + (size_t)(j0 + 64) * 64);
            pk1 = *(const bf16x8*)(Kg + (size_t)(j0 + 64) * 64 + 8);
            pv0 = *(const bf16x8*)(Vg + j0 + 64);
            pv1 = *(const bf16x8*)(Vg + j0 + 72);
        }

        if (j0 <= q0a)
            attn_step(Kb, Vb, qfA0, qfA1, lpa, oa, qwA, j0, j0 == q0a, col, g, c7);
        attn_step(Kb, Vb, qfB0, qfB1, lpb, ob, qwB, j0, j0 == q0b, col, g, c7);
    }

    // epilogue: l[q=qw+col] lives replicated in the 4 g-lanes of each col group;
    // reduce across g (xor 16/32), then gather l for q=4g+r via lane shuffle.
    float la = lpa; la += __shfl_xor(la, 16); la += __shfl_xor(la, 32);
    float lb = lpb; lb += __shfl_xor(lb, 16); lb += __shfl_xor(lb, 32);
    const int b = bh >> 3, h = bh & 7;
    #pragma unroll
    for (int r = 0; r < 4; ++r) {
        const float inva = 1.f / __shfl(la, 4 * g + r);
        const float invb = 1.f / __shfl(lb, 4 * g + r);
        const size_t rowa = ((size_t)b * 2048 + qwA + 4 * g + r) * 512 + h * 64;
        const size_t rowb = ((size_t)b * 2048 + qwB + 4 * g + r) * 512 + h * 64;
        #pragma unroll
        for (int nt = 0; nt < 4; ++nt) {
            ctxb[rowa + nt * 16 + col] = f2bf(oa[nt][r] * inva);
            ctxb[rowb + nt * 16 + col] = f2bf(ob[nt][r] * invb);
        }
    }
}

// ---------------- LayerNorm(residual): out = LN(A + B1) * g + beta  (2-input)
template<int WRITE_BF16>
__global__ void ln_residual(const float* __restrict__ A, const float* __restrict__ B1,
                            const float* __restrict__ g, const float* __restrict__ beta,
                            float* __restrict__ out, ushort* __restrict__ outb) {
    __shared__ float sbuf[8];
    const int row = blockIdx.x;
    const int tid = threadIdx.x;
    const size_t base = (size_t)row * D_MODEL;

    float v0 = A[base + tid]       + B1[base + tid];
    float v1 = A[base + tid + 256] + B1[base + tid + 256];

    float sum = v0 + v1;
    #pragma unroll
    for (int off = 32; off; off >>= 1) sum += __shfl_xor(sum, off);
    if ((tid & 63) == 0) sbuf[tid >> 6] = sum;
    __syncthreads();
    if (tid == 0) { float t = 0.f; for (int i = 0; i < 4; ++i) t += sbuf[i]; sbuf[4] = t; }
    __syncthreads();
    const float mu = sbuf[4] * (1.f / 512.f);
    __syncthreads();

    float d0 = v0 - mu, d1 = v1 - mu;
    float sq = d0 * d0 + d1 * d1;
    #pragma unroll
    for (int off = 32; off; off >>= 1) sq += __shfl_xor(sq, off);
    if ((tid & 63) == 0) sbuf[tid >> 6] = sq;
    __syncthreads();
    if (tid == 0) { float t = 0.f; for (int i = 0; i < 4; ++i) t += sbuf[i]; sbuf[4] = t; }
    __syncthreads();
    const float var = sbuf[4] * (1.f / 512.f);
    const float rs  = rsqrtf(var + 1e-5f);

    float r0 = d0 * rs * g[tid]       + beta[tid];
    float r1 = d1 * rs * g[tid + 256] + beta[tid + 256];
    out[base + tid]       = r0;
    out[base + tid + 256] = r1;
    if (WRITE_BF16) {
        outb[base + tid]       = f2bf(r0);
        outb[base + tid + 256] = f2bf(r1);
    }
}

extern "C" void kernel_launch(void* const* d_in, const int* in_sizes, int n_in,
                              void* d_out, int out_size, void* d_ws, size_t ws_size,
                              hipStream_t stream) {
    const float* x    = (const float*)d_in[0];
    const float* Wqkv = (const float*)d_in[1];
    const float* bqkv = (const float*)d_in[2];
    const float* Wo   = (const float*)d_in[3];
    const float* bo   = (const float*)d_in[4];
    const float* W1   = (const float*)d_in[5];
    const float* b1   = (const float*)d_in[6];
    const float* W2   = (const float*)d_in[7];
    const float* b2   = (const float*)d_in[8];
    const float* g1   = (const float*)d_in[9];
    const float* bn1  = (const float*)d_in[10];
    const float* g2   = (const float*)d_in[11];
    const float* bn2  = (const float*)d_in[12];

    float* ws = (float*)d_ws;
    // time-multiplexed layout (floats):
    // [0,6291456)    Qcb/Kcb/Vtb (steps 1-2); ff1b [0,8388608) (steps 5-6)
    // [8388608,12582912)  ff2a (steps 6-7)
    // [12582912,16777216) attn_a (steps 3-4)
    // [16777216,20971520) ln1 fp32
    // [20971520,...) ctxb, ln1b, xb, Wqkvb, Wob, W1b, W2b (bf16)
    ushort* Qcb     = (ushort*)ws;
    ushort* Kcb     = (ushort*)(ws + 2097152);
    ushort* Vtb     = (ushort*)(ws + 4194304);
    ushort* ff1b    = (ushort*)ws;
    float*  ff2a    = ws + 8388608;
    float*  attn_a  = ws + 12582912;
    float*  ln1     = ws + 16777216;
    ushort* ctxb  = (ushort*)(ws + 20971520);
    ushort* ln1b  = (ushort*)(ws + 23068672);
    ushort* xb    = (ushort*)(ws + 25165824);
    ushort* Wqkvb = (ushort*)(ws + 27262976);
    float*  out   = (float*)d_out;
    ushort* W1b   = (ushort*)(ws + 27787264);
    ushort* W2b   = (ushort*)(ws + 28311552);
    ushort* Wob   = (ushort*)(ws + 27656192);

    const dim3 blk(256);

    // 0. fused casts (xb..W2b contiguous from xb)
    cast_all_bf16<<<dim3(7168), blk, 0, stream>>>(x, Wqkv, Wo, W1, W2, xb);

    // 1. QKV projection -> split Qc/Kc/Vt bf16 (128x128 tiles)
    gemm_bt_mfma<2,0,128><<<dim3(1536/128, 8192/128), blk, 0, stream>>>(
        xb, Wqkvb, bqkv, nullptr, Qcb, Kcb, Vtb, TOKENS, 1536, 512, 512);
    // 2. MFMA flash attention (paired q-tiles, XCD-swizzled 1D grid) -> ctxb bf16
    attn_mfma_kernel<<<dim3(512), blk, 0, stream>>>(Qcb, Kcb, Vtb, ctxb);
    // 3. output projection, full-K 64x128 tiles -> attn_a fp32 (+bias)
    gemm_bt_mfma<3,0,64><<<dim3(512/128, 8192/64), blk, 0, stream>>>(
        ctxb, Wob, bo, attn_a, nullptr, nullptr, nullptr, TOKENS, 512, 512, 512);
    // 4. LN1(x + attn_a) -> ln1 fp32 + ln1b bf16
    ln_residual<1><<<dim3(TOKENS), blk, 0, stream>>>(x, attn_a, g1, bn1, ln1, ln1b);
    // 5. FF1 + ReLU -> ff1b bf16 [8192,2048] (128x128 tiles)
    gemm_bt_mfma<1,1,128><<<dim3(2048/128, 8192/128), blk, 0, stream>>>(
        ln1b, W1b, b1, ff1b, nullptr, nullptr, nullptr, TOKENS, 2048, 512, 512);
    // 6. FF2, full-K 64x128 tiles -> ff2a fp32 (+bias)
    gemm_bt_mfma<3,0,64><<<dim3(512/128, 8192/64), blk, 0, stream>>>(
        ff1b, W2b, b2, ff2a, nullptr, nullptr, nullptr, TOKENS, 512, 2048, 2048);
    // 7. LN2(ln1 + ff2a) -> out
    ln_residual<0><<<dim3(TOKENS), blk, 0, stream>>>(ln1, ff2a, g2, bn2, out, nullptr);
}